// Round 14
// baseline (281.580 us; speedup 1.0000x reference)
//
#include <hip/hip_runtime.h>
#include <stdio.h>

#define NBP   8192
#define MTOT  8192
#define CIN   64
#define CO    128

#define EPR(...) do { fprintf(stderr, __VA_ARGS__); fflush(stderr); } while (0)

typedef short short8 __attribute__((ext_vector_type(8)));
typedef float floatx4 __attribute__((ext_vector_type(4)));
typedef unsigned short ushort;
typedef ushort ushort4v __attribute__((ext_vector_type(4)));

__device__ __forceinline__ ushort f2b(float f)   // RNE f32->bf16
{
    union { unsigned int i; float f; } x; x.f = f;
    return (ushort)((x.i + 0x7fffu + ((x.i >> 16) & 1u)) >> 16);
}
__device__ __forceinline__ float b2f(ushort u)
{
    union { unsigned int i; float f; } x; x.i = ((unsigned int)u) << 16;
    return x.f;
}
__device__ __forceinline__ void split_rne(float v, ushort& h, ushort& l)
{
    ushort hh = f2b(v);
    h = hh; l = f2b(v - b2f(hh));
}

// ---------------------------------------------------------------------------
// Kernel 1 (merged): blocks 0..2047 = ball query (f64 d2, bit-identical);
// blocks 2048..4095 = prep (zero 16-copy stat buffers, copy new_xyz to out,
// split weights hi/lo, bf16-convert features).
// ---------------------------------------------------------------------------
__global__ void __launch_bounds__(256, 1) StackSAModuleMSG_85761906966880_kernel(
    const float* __restrict__ xyz, const float* __restrict__ nxyz,
    float* __restrict__ out, float* __restrict__ scop,
    const float* __restrict__ feat, ushort* __restrict__ fh,
    int* __restrict__ idx0, int* __restrict__ idx1,
    int* __restrict__ empty0, int* __restrict__ empty1,
    const float* __restrict__ w00, const float* __restrict__ w01,
    const float* __restrict__ w10, const float* __restrict__ w11,
    ushort* __restrict__ wh00, ushort* __restrict__ wl00,
    ushort* __restrict__ wh01, ushort* __restrict__ wl01,
    ushort* __restrict__ wh10, ushort* __restrict__ wl10,
    ushort* __restrict__ wh11, ushort* __restrict__ wl11)
{
    if (blockIdx.x < MTOT/4) {
        // ---------------- ball query ----------------
        const double r2a = 0.2 * 0.2;
        const double r2b = 0.4 * 0.4;
        int m    = blockIdx.x * 4 + (threadIdx.x >> 6);
        int lane = threadIdx.x & 63;
        int b    = m >> 11;
        int base = b * NBP;

        double nx = (double)nxyz[3*m+0];
        double ny = (double)nxyz[3*m+1];
        double nz = (double)nxyz[3*m+2];
        double nn = nx*nx + ny*ny + nz*nz;

        int cnt0 = 0, cnt1 = 0;
        int first0 = base, first1 = base;
        unsigned long long lt = (1ull << lane) - 1ull;

        for (int j = 0; j < NBP; j += 64) {
            int gi = base + j + lane;
            double px = (double)xyz[3*gi+0];
            double py = (double)xyz[3*gi+1];
            double pz = (double)xyz[3*gi+2];
            double pp = px*px + py*py + pz*pz;
            double dt = nx*px + ny*py + nz*pz;
            double d2 = nn + pp - 2.0*dt;
            bool in0 = d2 < r2a;
            bool in1 = d2 < r2b;
            unsigned long long m0 = __ballot(in0);
            unsigned long long m1 = __ballot(in1);
            if (in0) {
                int p0 = cnt0 + __popcll(m0 & lt);
                if (p0 < 16) idx0[m*16 + p0] = gi;
            }
            if (in1) {
                int p1 = cnt1 + __popcll(m1 & lt);
                if (p1 < 32) idx1[m*32 + p1] = gi;
            }
            if (cnt0 == 0 && m0) first0 = base + j + (__ffsll((long long)m0) - 1);
            if (cnt1 == 0 && m1) first1 = base + j + (__ffsll((long long)m1) - 1);
            cnt0 += __popcll(m0);
            cnt1 += __popcll(m1);
            if (cnt0 >= 16 && cnt1 >= 32) break;
        }
        int c0 = cnt0 < 16 ? cnt0 : 16;
        int c1 = cnt1 < 32 ? cnt1 : 32;
        if (lane >= c0 && lane < 16) idx0[m*16 + lane] = first0;
        if (lane >= c1 && lane < 32) idx1[m*32 + lane] = first1;
        if (lane == 0) { empty0[m] = (cnt0 == 0); empty1[m] = (cnt1 == 0); }
    } else {
        // ---------------- prep ----------------
        int i = (blockIdx.x - MTOT/4) * 256 + threadIdx.x;
        if (i < 16384) scop[i] = 0.f;   // 4 groups x 16 copies x 256 ch
        if (i < MTOT*3) out[i] = nxyz[i];
        if (i < 128*128) {
            split_rne(w01[i], wh01[i], wl01[i]);
            split_rne(w11[i], wh11[i], wl11[i]);
        }
        if (i < 128*96) {
            int o = i / 96, kd = i - o*96;
            int c = (kd < 64) ? (kd + 3) : ((kd < 67) ? (kd - 64) : -1);
            float a = (c >= 0) ? w00[o*67 + c] : 0.f;
            split_rne(a, wh00[i], wl00[i]);
            float b = (c >= 0) ? w10[o*67 + c] : 0.f;
            split_rne(b, wh10[i], wl10[i]);
        }
        // feature hi-convert: thread i handles 4 consecutive floats
        {
            float4 v = *(const float4*)(feat + (size_t)4*i);
            ushort4v h;
            h[0] = f2b(v.x); h[1] = f2b(v.y); h[2] = f2b(v.z); h[3] = f2b(v.w);
            *(ushort4v*)(fh + (size_t)4*i) = h;
        }
    }
}

// ---------------------------------------------------------------------------
// Shared 128-row gather (hi only).
// ---------------------------------------------------------------------------
template<int NS, int GM>
__device__ __forceinline__ void gather128(
    const ushort* __restrict__ fh,
    const float* __restrict__ xyz, const float* __restrict__ nxyz,
    const int* __restrict__ idx, unsigned em, int m0, int t, ushort* ah)
{
    constexpr int ROWS = NS*GM;   // 128
    const long long ib = (long long)m0 * NS;
    const short8 Z8 = {0,0,0,0,0,0,0,0};
#pragma unroll
    for (int e = t; e < ROWS*8; e += 256) {
        int n = e >> 3, c8 = e & 7;
        int gi = idx[ib + n];
        short8 v = *(const short8*)(fh + (size_t)gi*CIN + 8*c8);
        if ((em >> (n / NS)) & 1u) v = Z8;
        *(short8*)(ah + n*136 + 8*c8) = v;
    }
#pragma unroll
    for (int e = t; e < ROWS*4; e += 256) {
        int n = e >> 2, k3 = e & 3;
        short8 v = Z8;
        if (k3 == 0) {
            int g = n / NS;
            if (!((em >> g) & 1u)) {
                int gi = idx[ib + n];
#pragma unroll
                for (int c = 0; c < 3; c++)
                    v[c] = (short)f2b(xyz[3*gi+c] - nxyz[3*(m0+g)+c]);
            }
        }
        *(short8*)(ah + n*136 + 64 + 8*k3) = v;
    }
}

// ---------------------------------------------------------------------------
// Stats pass, serial 2-tile per block: weights loaded ONCE, reused for both
// tiles. 16-copy atomic staging for partial sums.
// ---------------------------------------------------------------------------
template<int NS, int GM>
__device__ __forceinline__ void stats1_pair(
    const ushort* __restrict__ fh,
    const float* __restrict__ xyz, const float* __restrict__ nxyz,
    const int* __restrict__ idx, const int* __restrict__ empty,
    const ushort* __restrict__ wh0, float* __restrict__ sdst,
    int tile0, int t, ushort* ah)
{
    int wv = t >> 6, lane = t & 63, l16 = lane & 15, qo = lane >> 4;
    int n0 = 32*wv;

    // ---- weights once per block ----
    short8 bh[3][2];
#pragma unroll
    for (int ks = 0; ks < 3; ks++)
#pragma unroll
        for (int nt = 0; nt < 2; nt++)
            bh[ks][nt] = *(const short8*)(wh0 +
                (long long)(n0 + 16*nt + l16)*96 + ks*32 + qo*8);

    for (int it = 0; it < 2; it++) {
        int bx = tile0 + it;
        int m0 = bx * GM;
        unsigned em = 0;
#pragma unroll
        for (int g = 0; g < GM; g++) em |= (empty[m0 + g] ? 1u : 0u) << g;
        gather128<NS, GM>(fh, xyz, nxyz, idx, em, m0, t, ah);
        __syncthreads();

        floatx4 acc[8][2];
#pragma unroll
        for (int i = 0; i < 8; i++) {
            acc[i][0] = (floatx4){0.f,0.f,0.f,0.f};
            acc[i][1] = (floatx4){0.f,0.f,0.f,0.f};
        }
#pragma unroll
        for (int ks = 0; ks < 3; ks++) {
            int kb = ks*32 + qo*8;
#pragma unroll
            for (int mt = 0; mt < 8; mt++) {
                int ao = (16*mt + l16)*136 + kb;
                short8 fh8 = *(const short8*)(ah + ao);
#pragma unroll
                for (int nt = 0; nt < 2; nt++)
                    acc[mt][nt] = __builtin_amdgcn_mfma_f32_16x16x32_bf16(
                                      fh8, bh[ks][nt], acc[mt][nt], 0, 0, 0);
            }
        }

        float sum[2] = {0.f,0.f}, sq[2] = {0.f,0.f};
#pragma unroll
        for (int mt = 0; mt < 8; mt++)
#pragma unroll
            for (int nt = 0; nt < 2; nt++)
#pragma unroll
                for (int r = 0; r < 4; r++) {
                    float a = acc[mt][nt][r];
                    sum[nt] += a; sq[nt] = fmaf(a, a, sq[nt]);
                }
#pragma unroll
        for (int nt = 0; nt < 2; nt++) {
            sum[nt] += __shfl_xor(sum[nt], 16); sum[nt] += __shfl_xor(sum[nt], 32);
            sq[nt]  += __shfl_xor(sq[nt],  16); sq[nt]  += __shfl_xor(sq[nt],  32);
        }
        if (lane < 16) {
            float* dst = sdst + (bx & 15) * 256;
#pragma unroll
            for (int nt = 0; nt < 2; nt++) {
                int c = n0 + 16*nt + lane;
                atomicAdd(&dst[c],       sum[nt]);
                atomicAdd(&dst[128 + c], sq[nt]);
            }
        }
        __syncthreads();   // LDS safe for next tile's gather
    }
}

__global__ void __launch_bounds__(256, 4) sa_stats1_both(
    const ushort* __restrict__ fh,
    const float* __restrict__ xyz, const float* __restrict__ nxyz,
    const int* __restrict__ idx0, const int* __restrict__ empty0,
    const ushort* __restrict__ wh00,
    const int* __restrict__ idx1, const int* __restrict__ empty1,
    const ushort* __restrict__ wh10, float* __restrict__ scop)
{
    __shared__ ushort ah[128*136];
    int t = threadIdx.x;
    if (blockIdx.x < 512)
        stats1_pair<16,8>(fh, xyz, nxyz, idx0, empty0, wh00,
                          scop + 0, 2*blockIdx.x, t, ah);
    else
        stats1_pair<32,4>(fh, xyz, nxyz, idx1, empty1, wh10,
                          scop + 4096, 2*(blockIdx.x - 512), t, ah);
}

// ---------------------------------------------------------------------------
// Fused pass, serial 2-tile per block: BN k/s prep once; per tile the full
// R13 body (chunked 2-slot weight streaming, cvt_pk writeback, 2-term GEMMs,
// 16-copy atomic staging for stats2, max/min stores).
// ---------------------------------------------------------------------------
template<int NS, int GM>
__device__ __forceinline__ void fused_tile(
    const ushort* __restrict__ fh,
    const float* __restrict__ xyz, const float* __restrict__ nxyz,
    const int* __restrict__ idx, const int* __restrict__ empty,
    const ushort* __restrict__ wh0, const ushort* __restrict__ wl0,
    const ushort* __restrict__ wh1, const ushort* __restrict__ wl1,
    float* __restrict__ s2dst,
    float* __restrict__ mxo, float* __restrict__ mno,
    int bx, int t, ushort* ah, const float* kv, const float* sv)
{
    const int TPG = NS/16;
    int m0 = bx * GM;
    int wv = t >> 6, lane = t & 63, l16 = lane & 15, qo = lane >> 4;
    int n0 = 32*wv;

    const long long wrow0 = (long long)(n0 + l16);
    const long long wrow1 = (long long)(n0 + 16 + l16);

    short8 wsh[2][2], wsl[2][2];
#pragma unroll
    for (int ks = 0; ks < 2; ks++) {
        wsh[ks][0] = *(const short8*)(wh0 + wrow0*96 + ks*32 + qo*8);
        wsl[ks][0] = *(const short8*)(wl0 + wrow0*96 + ks*32 + qo*8);
        wsh[ks][1] = *(const short8*)(wh0 + wrow1*96 + ks*32 + qo*8);
        wsl[ks][1] = *(const short8*)(wl0 + wrow1*96 + ks*32 + qo*8);
    }

    unsigned em = 0;
#pragma unroll
    for (int g = 0; g < GM; g++) em |= (empty[m0 + g] ? 1u : 0u) << g;
    gather128<NS, GM>(fh, xyz, nxyz, idx, em, m0, t, ah);
    __syncthreads();   // barrier 1

    floatx4 acc[8][2];
#pragma unroll
    for (int i = 0; i < 8; i++) {
        acc[i][0] = (floatx4){0.f,0.f,0.f,0.f};
        acc[i][1] = (floatx4){0.f,0.f,0.f,0.f};
    }

    // GEMM1 ks=0 (slot 0)
#pragma unroll
    for (int mt = 0; mt < 8; mt++) {
        short8 fh8 = *(const short8*)(ah + (16*mt + l16)*136 + qo*8);
#pragma unroll
        for (int nt = 0; nt < 2; nt++) {
            acc[mt][nt] = __builtin_amdgcn_mfma_f32_16x16x32_bf16(
                              fh8, wsl[0][nt], acc[mt][nt], 0, 0, 0);
            acc[mt][nt] = __builtin_amdgcn_mfma_f32_16x16x32_bf16(
                              fh8, wsh[0][nt], acc[mt][nt], 0, 0, 0);
        }
    }
    wsh[0][0] = *(const short8*)(wh0 + wrow0*96 + 64 + qo*8);
    wsl[0][0] = *(const short8*)(wl0 + wrow0*96 + 64 + qo*8);
    wsh[0][1] = *(const short8*)(wh0 + wrow1*96 + 64 + qo*8);
    wsl[0][1] = *(const short8*)(wl0 + wrow1*96 + 64 + qo*8);
    // GEMM1 ks=1 (slot 1)
#pragma unroll
    for (int mt = 0; mt < 8; mt++) {
        short8 fh8 = *(const short8*)(ah + (16*mt + l16)*136 + 32 + qo*8);
#pragma unroll
        for (int nt = 0; nt < 2; nt++) {
            acc[mt][nt] = __builtin_amdgcn_mfma_f32_16x16x32_bf16(
                              fh8, wsl[1][nt], acc[mt][nt], 0, 0, 0);
            acc[mt][nt] = __builtin_amdgcn_mfma_f32_16x16x32_bf16(
                              fh8, wsh[1][nt], acc[mt][nt], 0, 0, 0);
        }
    }
    // GEMM1 ks=2 (slot 0)
#pragma unroll
    for (int mt = 0; mt < 8; mt++) {
        short8 fh8 = *(const short8*)(ah + (16*mt + l16)*136 + 64 + qo*8);
#pragma unroll
        for (int nt = 0; nt < 2; nt++) {
            acc[mt][nt] = __builtin_amdgcn_mfma_f32_16x16x32_bf16(
                              fh8, wsl[0][nt], acc[mt][nt], 0, 0, 0);
            acc[mt][nt] = __builtin_amdgcn_mfma_f32_16x16x32_bf16(
                              fh8, wsh[0][nt], acc[mt][nt], 0, 0, 0);
        }
    }

    __syncthreads();   // barrier 2

    // writeback h via hardware packed cvt (RNE, = f2b)
#pragma unroll
    for (int nt = 0; nt < 2; nt++) {
        int c = n0 + 16*nt + l16;
        float k = kv[c], s = sv[c];
#pragma unroll
        for (int mt = 0; mt < 8; mt++) {
            int rbase = 16*mt + qo*4;
#pragma unroll
            for (int r = 0; r < 4; r += 2) {
                float h0 = fmaxf(fmaf(acc[mt][nt][r],   k, s), 0.f);
                float h1 = fmaxf(fmaf(acc[mt][nt][r+1], k, s), 0.f);
                unsigned int pk;
                asm("v_cvt_pk_bf16_f32 %0, %1, %2"
                    : "=v"(pk) : "v"(h0), "v"(h1));
                ah[(rbase + r    )*136 + c] = (ushort)(pk & 0xffffu);
                ah[(rbase + r + 1)*136 + c] = (ushort)(pk >> 16);
            }
        }
    }

    // GEMM2 preload slots {0,1}
#pragma unroll
    for (int ks = 0; ks < 2; ks++) {
        wsh[ks][0] = *(const short8*)(wh1 + wrow0*128 + ks*32 + qo*8);
        wsl[ks][0] = *(const short8*)(wl1 + wrow0*128 + ks*32 + qo*8);
        wsh[ks][1] = *(const short8*)(wh1 + wrow1*128 + ks*32 + qo*8);
        wsl[ks][1] = *(const short8*)(wl1 + wrow1*128 + ks*32 + qo*8);
    }
    __syncthreads();   // barrier 3

#pragma unroll
    for (int i = 0; i < 8; i++) {
        acc[i][0] = (floatx4){0.f,0.f,0.f,0.f};
        acc[i][1] = (floatx4){0.f,0.f,0.f,0.f};
    }
    // ks=0 (slot 0)
#pragma unroll
    for (int mt = 0; mt < 8; mt++) {
        short8 fh8 = *(const short8*)(ah + (16*mt + l16)*136 + qo*8);
#pragma unroll
        for (int nt = 0; nt < 2; nt++) {
            acc[mt][nt] = __builtin_amdgcn_mfma_f32_16x16x32_bf16(
                              fh8, wsl[0][nt], acc[mt][nt], 0, 0, 0);
            acc[mt][nt] = __builtin_amdgcn_mfma_f32_16x16x32_bf16(
                              fh8, wsh[0][nt], acc[mt][nt], 0, 0, 0);
        }
    }
    wsh[0][0] = *(const short8*)(wh1 + wrow0*128 + 64 + qo*8);
    wsl[0][0] = *(const short8*)(wl1 + wrow0*128 + 64 + qo*8);
    wsh[0][1] = *(const short8*)(wh1 + wrow1*128 + 64 + qo*8);
    wsl[0][1] = *(const short8*)(wl1 + wrow1*128 + 64 + qo*8);
    // ks=1 (slot 1)
#pragma unroll
    for (int mt = 0; mt < 8; mt++) {
        short8 fh8 = *(const short8*)(ah + (16*mt + l16)*136 + 32 + qo*8);
#pragma unroll
        for (int nt = 0; nt < 2; nt++) {
            acc[mt][nt] = __builtin_amdgcn_mfma_f32_16x16x32_bf16(
                              fh8, wsl[1][nt], acc[mt][nt], 0, 0, 0);
            acc[mt][nt] = __builtin_amdgcn_mfma_f32_16x16x32_bf16(
                              fh8, wsh[1][nt], acc[mt][nt], 0, 0, 0);
        }
    }
    wsh[1][0] = *(const short8*)(wh1 + wrow0*128 + 96 + qo*8);
    wsl[1][0] = *(const short8*)(wl1 + wrow0*128 + 96 + qo*8);
    wsh[1][1] = *(const short8*)(wh1 + wrow1*128 + 96 + qo*8);
    wsl[1][1] = *(const short8*)(wl1 + wrow1*128 + 96 + qo*8);
    // ks=2 (slot 0)
#pragma unroll
    for (int mt = 0; mt < 8; mt++) {
        short8 fh8 = *(const short8*)(ah + (16*mt + l16)*136 + 64 + qo*8);
#pragma unroll
        for (int nt = 0; nt < 2; nt++) {
            acc[mt][nt] = __builtin_amdgcn_mfma_f32_16x16x32_bf16(
                              fh8, wsl[0][nt], acc[mt][nt], 0, 0, 0);
            acc[mt][nt] = __builtin_amdgcn_mfma_f32_16x16x32_bf16(
                              fh8, wsh[0][nt], acc[mt][nt], 0, 0, 0);
        }
    }
    // ks=3 (slot 1)
#pragma unroll
    for (int mt = 0; mt < 8; mt++) {
        short8 fh8 = *(const short8*)(ah + (16*mt + l16)*136 + 96 + qo*8);
#pragma unroll
        for (int nt = 0; nt < 2; nt++) {
            acc[mt][nt] = __builtin_amdgcn_mfma_f32_16x16x32_bf16(
                              fh8, wsl[1][nt], acc[mt][nt], 0, 0, 0);
            acc[mt][nt] = __builtin_amdgcn_mfma_f32_16x16x32_bf16(
                              fh8, wsh[1][nt], acc[mt][nt], 0, 0, 0);
        }
    }

    // epilogue: stats2 (16-copy atomic staging) + per-group max/min
    float sum[2] = {0.f,0.f}, sq[2] = {0.f,0.f};
    float Mx[GM][2], Mn[GM][2];
#pragma unroll
    for (int g = 0; g < GM; g++) {
        Mx[g][0] = -3.4e38f; Mx[g][1] = -3.4e38f;
        Mn[g][0] =  3.4e38f; Mn[g][1] =  3.4e38f;
    }
#pragma unroll
    for (int mt = 0; mt < 8; mt++) {
        int gg = mt / TPG;
#pragma unroll
        for (int nt = 0; nt < 2; nt++)
#pragma unroll
            for (int r = 0; r < 4; r++) {
                float a = acc[mt][nt][r];
                sum[nt] += a; sq[nt] = fmaf(a, a, sq[nt]);
                Mx[gg][nt] = fmaxf(Mx[gg][nt], a);
                Mn[gg][nt] = fminf(Mn[gg][nt], a);
            }
    }
#pragma unroll
    for (int nt = 0; nt < 2; nt++) {
        sum[nt] += __shfl_xor(sum[nt], 16); sum[nt] += __shfl_xor(sum[nt], 32);
        sq[nt]  += __shfl_xor(sq[nt],  16); sq[nt]  += __shfl_xor(sq[nt],  32);
#pragma unroll
        for (int g = 0; g < GM; g++) {
            Mx[g][nt] = fmaxf(Mx[g][nt], __shfl_xor(Mx[g][nt], 16));
            Mx[g][nt] = fmaxf(Mx[g][nt], __shfl_xor(Mx[g][nt], 32));
            Mn[g][nt] = fminf(Mn[g][nt], __shfl_xor(Mn[g][nt], 16));
            Mn[g][nt] = fminf(Mn[g][nt], __shfl_xor(Mn[g][nt], 32));
        }
    }
    if (lane < 16) {
        float* dst = s2dst + (bx & 15) * 256;
#pragma unroll
        for (int nt = 0; nt < 2; nt++) {
            int c = n0 + 16*nt + lane;
            atomicAdd(&dst[c],       sum[nt]);
            atomicAdd(&dst[128 + c], sq[nt]);
#pragma unroll
            for (int g = 0; g < GM; g++) {
                mxo[(long long)(m0+g)*128 + c] = Mx[g][nt];
                mno[(long long)(m0+g)*128 + c] = Mn[g][nt];
            }
        }
    }
    __syncthreads();   // LDS safe for next tile's gather
}

template<int NS, int GM>
__device__ __forceinline__ void fused_pair(
    const ushort* __restrict__ fh,
    const float* __restrict__ xyz, const float* __restrict__ nxyz,
    const int* __restrict__ idx, const int* __restrict__ empty,
    const ushort* __restrict__ wh0, const ushort* __restrict__ wl0,
    const ushort* __restrict__ wh1, const ushort* __restrict__ wl1,
    const float* __restrict__ g0, const float* __restrict__ b0,
    const float* __restrict__ s1cop, float* __restrict__ s2dst,
    float* __restrict__ mxo, float* __restrict__ mno,
    float invN, int tile0, int t,
    ushort* ah, float* kv, float* sv)
{
    // ---- BN k/s once per block ----
    if (t < 128) {
        float sm = 0.f, sqv = 0.f;
#pragma unroll
        for (int cp = 0; cp < 16; cp++) {
            sm  += s1cop[cp*256 + t];
            sqv += s1cop[cp*256 + 128 + t];
        }
        float mean = sm * invN;
        float var  = sqv * invN - mean * mean;
        float k    = rsqrtf(var + 1e-5f) * g0[t];
        kv[t] = k;
        sv[t] = b0[t] - mean * k;
    }
    // kv/sv visible to all threads after fused_tile's barrier 1.
    for (int it = 0; it < 2; it++)
        fused_tile<NS, GM>(fh, xyz, nxyz, idx, empty,
                           wh0, wl0, wh1, wl1, s2dst, mxo, mno,
                           tile0 + it, t, ah, kv, sv);
}

__global__ void __launch_bounds__(256, 4) sa_fused_both(
    const ushort* __restrict__ fh,
    const float* __restrict__ xyz, const float* __restrict__ nxyz,
    const int* __restrict__ idx0, const int* __restrict__ empty0,
    const ushort* __restrict__ wh00, const ushort* __restrict__ wl00,
    const ushort* __restrict__ wh01, const ushort* __restrict__ wl01,
    const float* __restrict__ g00, const float* __restrict__ b00,
    float* __restrict__ mx0, float* __restrict__ mn0, float invN0,
    const int* __restrict__ idx1, const int* __restrict__ empty1,
    const ushort* __restrict__ wh10, const ushort* __restrict__ wl10,
    const ushort* __restrict__ wh11, const ushort* __restrict__ wl11,
    const float* __restrict__ g10, const float* __restrict__ b10,
    float* __restrict__ mx1, float* __restrict__ mn1, float invN1,
    float* __restrict__ scop)
{
    __shared__ ushort ah[128*136];
    __shared__ float kv[128], sv[128];
    int t = threadIdx.x;
    if (blockIdx.x < 512)
        fused_pair<16,8>(fh, xyz, nxyz, idx0, empty0,
                         wh00, wl00, wh01, wl01, g00, b00,
                         scop + 0, scop + 8192,
                         mx0, mn0, invN0, 2*blockIdx.x, t, ah, kv, sv);
    else
        fused_pair<32,4>(fh, xyz, nxyz, idx1, empty1,
                         wh10, wl10, wh11, wl11, g10, b10,
                         scop + 4096, scop + 12288,
                         mx1, mn1, invN1, 2*(blockIdx.x - 512), t, ah, kv, sv);
}

// ---------------------------------------------------------------------------
// Pass 3, reshaped: 1024 blocks x 8 rows. Each thread computes its channel's
// k/sh ONCE (16-copy sum) and reuses it for 8 outputs.
// ---------------------------------------------------------------------------
__global__ void __launch_bounds__(256, 1) sa_pass3b(
    const float* __restrict__ mx0, const float* __restrict__ mn0,
    const float* __restrict__ g01, const float* __restrict__ b01,
    const float* __restrict__ mx1, const float* __restrict__ mn1,
    const float* __restrict__ g11, const float* __restrict__ b11,
    const float* __restrict__ scop, float* __restrict__ outp,
    float invN0, float invN1)
{
    int t = threadIdx.x;
    int o = t;                 // output channel 0..255
    bool sc1 = o >= 128;
    int oc = o & 127;
    const float* sc = sc1 ? (scop + 12288) : (scop + 8192);
    float invN = sc1 ? invN1 : invN0;
    float gg   = sc1 ? g11[oc] : g01[oc];
    float bb   = sc1 ? b11[oc] : b01[oc];
    float sm = 0.f, sp = 0.f;
#pragma unroll
    for (int cp = 0; cp < 16; cp++) {
        sm += sc[cp*256 + oc];
        sp += sc[cp*256 + 128 + oc];
    }
    float mean = sm * invN;
    float var  = sp * invN - mean * mean;
    float k    = rsqrtf(var + 1e-5f) * gg;
    float sh   = bb - mean * k;
    const float* src = (k >= 0.f) ? (sc1 ? mx1 : mx0) : (sc1 ? mn1 : mn0);

    int m0 = blockIdx.x * 8;
#pragma unroll
    for (int j = 0; j < 8; j++) {
        int m = m0 + j;
        float v = src[(long long)m*128 + oc];
        float r = fmaf(v, k, sh);
        outp[(long long)m*256 + o] = r > 0.f ? r : 0.f;
    }
}

// ---------------------------------------------------------------------------
extern "C" void kernel_launch(void* const* d_in, const int* in_sizes, int n_in,
                              void* d_out, int out_size, void* d_ws, size_t ws_size,
                              hipStream_t stream)
{
    const float* xyz  = (const float*)d_in[0];
    const float* feat = (const float*)d_in[1];
    const float* nxyz = (const float*)d_in[2];
    const float* w00 = (const float*)d_in[5];
    const float* g00 = (const float*)d_in[6];
    const float* b00 = (const float*)d_in[7];
    const float* w01 = (const float*)d_in[8];
    const float* g01 = (const float*)d_in[9];
    const float* b01 = (const float*)d_in[10];
    const float* w10 = (const float*)d_in[11];
    const float* g10 = (const float*)d_in[12];
    const float* b10 = (const float*)d_in[13];
    const float* w11 = (const float*)d_in[14];
    const float* g11 = (const float*)d_in[15];
    const float* b11 = (const float*)d_in[16];
    float* out = (float*)d_out;

    char*  wsb    = (char*)d_ws;
    int*   idx0   = (int*)(wsb + 4096);
    int*   idx1   = (int*)(wsb + 4096 + 524288);
    int*   empty0 = (int*)(wsb + 4096 + 524288 + 1048576);
    int*   empty1 = (int*)(wsb + 4096 + 524288 + 1048576 + 32768);
    ushort* fh    = (ushort*)(wsb + 2000000);    // 4 MB
    float* mx0    = (float*)(wsb + 150000000);
    float* mn0    = (float*)(wsb + 155000000);
    float* mx1    = (float*)(wsb + 160000000);
    float* mn1    = (float*)(wsb + 165000000);
    ushort* wh01  = (ushort*)(wsb + 170000000);
    ushort* wl01  = (ushort*)(wsb + 171000000);
    ushort* wh11  = (ushort*)(wsb + 172000000);
    ushort* wl11  = (ushort*)(wsb + 173000000);
    ushort* wh00  = (ushort*)(wsb + 174000000);
    ushort* wl00  = (ushort*)(wsb + 175000000);
    ushort* wh10  = (ushort*)(wsb + 176000000);
    ushort* wl10  = (ushort*)(wsb + 177000000);
    float* scop   = (float*)(wsb + 180000000);   // 4 x 16 x 256 floats = 64 KB

    const float invN0 = 1.0f / (float)(MTOT*16);
    const float invN1 = 1.0f / (float)(MTOT*32);
    float* fout = out + MTOT*3;

    // 1: ballq (blocks 0..2047) + prep (blocks 2048..4095; zeroes scop)
    StackSAModuleMSG_85761906966880_kernel<<<MTOT/4 + 2048, 256, 0, stream>>>(
        xyz, nxyz, out, scop, feat, fh,
        idx0, idx1, empty0, empty1,
        w00, w01, w10, w11,
        wh00, wl00, wh01, wl01, wh10, wl10, wh11, wl11);

    // 2: stats1 -> 16-copy staging (serial 2-tile blocks)
    sa_stats1_both<<<1536, 256, 0, stream>>>(
        fh, xyz, nxyz,
        idx0, empty0, wh00,
        idx1, empty1, wh10, scop);

    // 3: fused (serial 2-tile blocks; reads s1 copies; writes s2 copies + max/min)
    sa_fused_both<<<1536, 256, 0, stream>>>(
        fh, xyz, nxyz,
        idx0, empty0, wh00, wl00, wh01, wl01, g00, b00,
        mx0, mn0, invN0,
        idx1, empty1, wh10, wl10, wh11, wl11, g10, b10,
        mx1, mn1, invN1, scop);

    // 4: pass3 (1024 blocks x 8 rows; per-thread k/sh computed once)
    sa_pass3b<<<1024, 256, 0, stream>>>(
        mx0, mn0, g01, b01, mx1, mn1, g11, b11, scop, fout, invN0, invN1);

    hipError_t e = hipGetLastError();
    if (e != hipSuccess) EPR("[KL] enqueue err=%d (%s)\n", (int)e, hipGetErrorString(e));
}

// Round 15
// 197.241 us; speedup vs baseline: 1.4276x; 1.4276x over previous
//
#include <hip/hip_runtime.h>
#include <stdio.h>

#define NBP   8192
#define MTOT  8192
#define CIN   64
#define CO    128

#define EPR(...) do { fprintf(stderr, __VA_ARGS__); fflush(stderr); } while (0)

typedef short short8 __attribute__((ext_vector_type(8)));
typedef float floatx4 __attribute__((ext_vector_type(4)));
typedef unsigned short ushort;
typedef ushort ushort4v __attribute__((ext_vector_type(4)));

__device__ __forceinline__ ushort f2b(float f)   // RNE f32->bf16
{
    union { unsigned int i; float f; } x; x.f = f;
    return (ushort)((x.i + 0x7fffu + ((x.i >> 16) & 1u)) >> 16);
}
__device__ __forceinline__ float b2f(ushort u)
{
    union { unsigned int i; float f; } x; x.i = ((unsigned int)u) << 16;
    return x.f;
}
__device__ __forceinline__ void split_rne(float v, ushort& h, ushort& l)
{
    ushort hh = f2b(v);
    h = hh; l = f2b(v - b2f(hh));
}

// ---------------------------------------------------------------------------
// Kernel 1 (merged): blocks 0..2047 = ball query (f64 d2, bit-identical);
// blocks 2048..4095 = prep (zero 16-copy stat buffers, copy new_xyz to out,
// split weights hi/lo, bf16-convert features).
// ---------------------------------------------------------------------------
__global__ void __launch_bounds__(256, 1) StackSAModuleMSG_85761906966880_kernel(
    const float* __restrict__ xyz, const float* __restrict__ nxyz,
    float* __restrict__ out, float* __restrict__ scop,
    const float* __restrict__ feat, ushort* __restrict__ fh,
    int* __restrict__ idx0, int* __restrict__ idx1,
    int* __restrict__ empty0, int* __restrict__ empty1,
    const float* __restrict__ w00, const float* __restrict__ w01,
    const float* __restrict__ w10, const float* __restrict__ w11,
    ushort* __restrict__ wh00, ushort* __restrict__ wl00,
    ushort* __restrict__ wh01, ushort* __restrict__ wl01,
    ushort* __restrict__ wh10, ushort* __restrict__ wl10,
    ushort* __restrict__ wh11, ushort* __restrict__ wl11)
{
    if (blockIdx.x < MTOT/4) {
        // ---------------- ball query ----------------
        const double r2a = 0.2 * 0.2;
        const double r2b = 0.4 * 0.4;
        int m    = blockIdx.x * 4 + (threadIdx.x >> 6);
        int lane = threadIdx.x & 63;
        int b    = m >> 11;
        int base = b * NBP;

        double nx = (double)nxyz[3*m+0];
        double ny = (double)nxyz[3*m+1];
        double nz = (double)nxyz[3*m+2];
        double nn = nx*nx + ny*ny + nz*nz;

        int cnt0 = 0, cnt1 = 0;
        int first0 = base, first1 = base;
        unsigned long long lt = (1ull << lane) - 1ull;

        for (int j = 0; j < NBP; j += 64) {
            int gi = base + j + lane;
            double px = (double)xyz[3*gi+0];
            double py = (double)xyz[3*gi+1];
            double pz = (double)xyz[3*gi+2];
            double pp = px*px + py*py + pz*pz;
            double dt = nx*px + ny*py + nz*pz;
            double d2 = nn + pp - 2.0*dt;
            bool in0 = d2 < r2a;
            bool in1 = d2 < r2b;
            unsigned long long m0 = __ballot(in0);
            unsigned long long m1 = __ballot(in1);
            if (in0) {
                int p0 = cnt0 + __popcll(m0 & lt);
                if (p0 < 16) idx0[m*16 + p0] = gi;
            }
            if (in1) {
                int p1 = cnt1 + __popcll(m1 & lt);
                if (p1 < 32) idx1[m*32 + p1] = gi;
            }
            if (cnt0 == 0 && m0) first0 = base + j + (__ffsll((long long)m0) - 1);
            if (cnt1 == 0 && m1) first1 = base + j + (__ffsll((long long)m1) - 1);
            cnt0 += __popcll(m0);
            cnt1 += __popcll(m1);
            if (cnt0 >= 16 && cnt1 >= 32) break;
        }
        int c0 = cnt0 < 16 ? cnt0 : 16;
        int c1 = cnt1 < 32 ? cnt1 : 32;
        if (lane >= c0 && lane < 16) idx0[m*16 + lane] = first0;
        if (lane >= c1 && lane < 32) idx1[m*32 + lane] = first1;
        if (lane == 0) { empty0[m] = (cnt0 == 0); empty1[m] = (cnt1 == 0); }
    } else {
        // ---------------- prep ----------------
        int i = (blockIdx.x - MTOT/4) * 256 + threadIdx.x;
        if (i < 16384) scop[i] = 0.f;   // 4 groups x 16 copies x 256 ch
        if (i < MTOT*3) out[i] = nxyz[i];
        if (i < 128*128) {
            split_rne(w01[i], wh01[i], wl01[i]);
            split_rne(w11[i], wh11[i], wl11[i]);
        }
        if (i < 128*96) {
            int o = i / 96, kd = i - o*96;
            int c = (kd < 64) ? (kd + 3) : ((kd < 67) ? (kd - 64) : -1);
            float a = (c >= 0) ? w00[o*67 + c] : 0.f;
            split_rne(a, wh00[i], wl00[i]);
            float b = (c >= 0) ? w10[o*67 + c] : 0.f;
            split_rne(b, wh10[i], wl10[i]);
        }
        // feature hi-convert: thread i handles 4 consecutive floats
        {
            float4 v = *(const float4*)(feat + (size_t)4*i);
            ushort4v h;
            h[0] = f2b(v.x); h[1] = f2b(v.y); h[2] = f2b(v.z); h[3] = f2b(v.w);
            *(ushort4v*)(fh + (size_t)4*i) = h;
        }
    }
}

// ---------------------------------------------------------------------------
// Shared 128-row gather (hi only).
// ---------------------------------------------------------------------------
template<int NS, int GM>
__device__ __forceinline__ void gather128(
    const ushort* __restrict__ fh,
    const float* __restrict__ xyz, const float* __restrict__ nxyz,
    const int* __restrict__ idx, unsigned em, int m0, int t, ushort* ah)
{
    constexpr int ROWS = NS*GM;   // 128
    const long long ib = (long long)m0 * NS;
    const short8 Z8 = {0,0,0,0,0,0,0,0};
#pragma unroll
    for (int e = t; e < ROWS*8; e += 256) {
        int n = e >> 3, c8 = e & 7;
        int gi = idx[ib + n];
        short8 v = *(const short8*)(fh + (size_t)gi*CIN + 8*c8);
        if ((em >> (n / NS)) & 1u) v = Z8;
        *(short8*)(ah + n*136 + 8*c8) = v;
    }
#pragma unroll
    for (int e = t; e < ROWS*4; e += 256) {
        int n = e >> 2, k3 = e & 3;
        short8 v = Z8;
        if (k3 == 0) {
            int g = n / NS;
            if (!((em >> g) & 1u)) {
                int gi = idx[ib + n];
#pragma unroll
                for (int c = 0; c < 3; c++)
                    v[c] = (short)f2b(xyz[3*gi+c] - nxyz[3*(m0+g)+c]);
            }
        }
        *(short8*)(ah + n*136 + 64 + 8*k3) = v;
    }
}

// ---------------------------------------------------------------------------
// Stats pass body: 128-row panel; partial sums -> 16-copy atomic staging.
// (R13-proven single-tile body; serial multi-tile spills — R14 lesson.)
// ---------------------------------------------------------------------------
template<int NS, int GM>
__device__ __forceinline__ void stats1_body(
    const ushort* __restrict__ fh,
    const float* __restrict__ xyz, const float* __restrict__ nxyz,
    const int* __restrict__ idx, const int* __restrict__ empty,
    const ushort* __restrict__ wh0, float* __restrict__ sdst,
    int bx, int t, ushort* ah)
{
    int m0 = bx * GM;
    int wv = t >> 6, lane = t & 63, l16 = lane & 15, qo = lane >> 4;
    int n0 = 32*wv;

    short8 bh[3][2];
#pragma unroll
    for (int ks = 0; ks < 3; ks++)
#pragma unroll
        for (int nt = 0; nt < 2; nt++)
            bh[ks][nt] = *(const short8*)(wh0 +
                (long long)(n0 + 16*nt + l16)*96 + ks*32 + qo*8);

    unsigned em = 0;
#pragma unroll
    for (int g = 0; g < GM; g++) em |= (empty[m0 + g] ? 1u : 0u) << g;
    gather128<NS, GM>(fh, xyz, nxyz, idx, em, m0, t, ah);
    __syncthreads();

    floatx4 acc[8][2];
#pragma unroll
    for (int i = 0; i < 8; i++) {
        acc[i][0] = (floatx4){0.f,0.f,0.f,0.f};
        acc[i][1] = (floatx4){0.f,0.f,0.f,0.f};
    }
#pragma unroll
    for (int ks = 0; ks < 3; ks++) {
        int kb = ks*32 + qo*8;
#pragma unroll
        for (int mt = 0; mt < 8; mt++) {
            int ao = (16*mt + l16)*136 + kb;
            short8 fh8 = *(const short8*)(ah + ao);
#pragma unroll
            for (int nt = 0; nt < 2; nt++)
                acc[mt][nt] = __builtin_amdgcn_mfma_f32_16x16x32_bf16(
                                  fh8, bh[ks][nt], acc[mt][nt], 0, 0, 0);
        }
    }

    float sum[2] = {0.f,0.f}, sq[2] = {0.f,0.f};
#pragma unroll
    for (int mt = 0; mt < 8; mt++)
#pragma unroll
        for (int nt = 0; nt < 2; nt++)
#pragma unroll
            for (int r = 0; r < 4; r++) {
                float a = acc[mt][nt][r];
                sum[nt] += a; sq[nt] = fmaf(a, a, sq[nt]);
            }
#pragma unroll
    for (int nt = 0; nt < 2; nt++) {
        sum[nt] += __shfl_xor(sum[nt], 16); sum[nt] += __shfl_xor(sum[nt], 32);
        sq[nt]  += __shfl_xor(sq[nt],  16); sq[nt]  += __shfl_xor(sq[nt],  32);
    }
    if (lane < 16) {
        float* dst = sdst + (bx & 15) * 256;
#pragma unroll
        for (int nt = 0; nt < 2; nt++) {
            int c = n0 + 16*nt + lane;
            atomicAdd(&dst[c],       sum[nt]);
            atomicAdd(&dst[128 + c], sq[nt]);
        }
    }
}

__global__ void __launch_bounds__(256, 4) sa_stats1_both(
    const ushort* __restrict__ fh,
    const float* __restrict__ xyz, const float* __restrict__ nxyz,
    const int* __restrict__ idx0, const int* __restrict__ empty0,
    const ushort* __restrict__ wh00,
    const int* __restrict__ idx1, const int* __restrict__ empty1,
    const ushort* __restrict__ wh10, float* __restrict__ scop)
{
    __shared__ ushort ah[128*136];
    int t = threadIdx.x;
    if (blockIdx.x < MTOT/8)
        stats1_body<16,8>(fh, xyz, nxyz, idx0, empty0, wh00,
                          scop + 0, blockIdx.x, t, ah);
    else
        stats1_body<32,4>(fh, xyz, nxyz, idx1, empty1, wh10,
                          scop + 4096, blockIdx.x - MTOT/8, t, ah);
}

// ---------------------------------------------------------------------------
// Fused body (R13-proven): 128-row panel, chunked 2-slot weight streaming;
// BN stats read by summing 16 staging copies; stats2 via 16-copy staging.
// ---------------------------------------------------------------------------
template<int NS, int GM>
__device__ __forceinline__ void fused_body(
    const ushort* __restrict__ fh,
    const float* __restrict__ xyz, const float* __restrict__ nxyz,
    const int* __restrict__ idx, const int* __restrict__ empty,
    const ushort* __restrict__ wh0, const ushort* __restrict__ wl0,
    const ushort* __restrict__ wh1, const ushort* __restrict__ wl1,
    const float* __restrict__ g0, const float* __restrict__ b0,
    const float* __restrict__ s1cop, float* __restrict__ s2dst,
    float* __restrict__ mxo, float* __restrict__ mno,
    float invN, int bx, int t,
    ushort* ah, float* kv, float* sv)
{
    const int TPG = NS/16;
    int m0 = bx * GM;
    int wv = t >> 6, lane = t & 63, l16 = lane & 15, qo = lane >> 4;
    int n0 = 32*wv;

    if (t < 128) {
        float sm = 0.f, sqv = 0.f;
#pragma unroll
        for (int cp = 0; cp < 16; cp++) {
            sm  += s1cop[cp*256 + t];
            sqv += s1cop[cp*256 + 128 + t];
        }
        float mean = sm * invN;
        float var  = sqv * invN - mean * mean;
        float k    = rsqrtf(var + 1e-5f) * g0[t];
        kv[t] = k;
        sv[t] = b0[t] - mean * k;
    }

    const long long wrow0 = (long long)(n0 + l16);
    const long long wrow1 = (long long)(n0 + 16 + l16);

    short8 wsh[2][2], wsl[2][2];
#pragma unroll
    for (int ks = 0; ks < 2; ks++) {
        wsh[ks][0] = *(const short8*)(wh0 + wrow0*96 + ks*32 + qo*8);
        wsl[ks][0] = *(const short8*)(wl0 + wrow0*96 + ks*32 + qo*8);
        wsh[ks][1] = *(const short8*)(wh0 + wrow1*96 + ks*32 + qo*8);
        wsl[ks][1] = *(const short8*)(wl0 + wrow1*96 + ks*32 + qo*8);
    }

    unsigned em = 0;
#pragma unroll
    for (int g = 0; g < GM; g++) em |= (empty[m0 + g] ? 1u : 0u) << g;
    gather128<NS, GM>(fh, xyz, nxyz, idx, em, m0, t, ah);
    __syncthreads();   // barrier 1

    floatx4 acc[8][2];
#pragma unroll
    for (int i = 0; i < 8; i++) {
        acc[i][0] = (floatx4){0.f,0.f,0.f,0.f};
        acc[i][1] = (floatx4){0.f,0.f,0.f,0.f};
    }

    // GEMM1 ks=0 (slot 0)
#pragma unroll
    for (int mt = 0; mt < 8; mt++) {
        short8 fh8 = *(const short8*)(ah + (16*mt + l16)*136 + qo*8);
#pragma unroll
        for (int nt = 0; nt < 2; nt++) {
            acc[mt][nt] = __builtin_amdgcn_mfma_f32_16x16x32_bf16(
                              fh8, wsl[0][nt], acc[mt][nt], 0, 0, 0);
            acc[mt][nt] = __builtin_amdgcn_mfma_f32_16x16x32_bf16(
                              fh8, wsh[0][nt], acc[mt][nt], 0, 0, 0);
        }
    }
    wsh[0][0] = *(const short8*)(wh0 + wrow0*96 + 64 + qo*8);
    wsl[0][0] = *(const short8*)(wl0 + wrow0*96 + 64 + qo*8);
    wsh[0][1] = *(const short8*)(wh0 + wrow1*96 + 64 + qo*8);
    wsl[0][1] = *(const short8*)(wl0 + wrow1*96 + 64 + qo*8);
    // GEMM1 ks=1 (slot 1)
#pragma unroll
    for (int mt = 0; mt < 8; mt++) {
        short8 fh8 = *(const short8*)(ah + (16*mt + l16)*136 + 32 + qo*8);
#pragma unroll
        for (int nt = 0; nt < 2; nt++) {
            acc[mt][nt] = __builtin_amdgcn_mfma_f32_16x16x32_bf16(
                              fh8, wsl[1][nt], acc[mt][nt], 0, 0, 0);
            acc[mt][nt] = __builtin_amdgcn_mfma_f32_16x16x32_bf16(
                              fh8, wsh[1][nt], acc[mt][nt], 0, 0, 0);
        }
    }
    // GEMM1 ks=2 (slot 0)
#pragma unroll
    for (int mt = 0; mt < 8; mt++) {
        short8 fh8 = *(const short8*)(ah + (16*mt + l16)*136 + 64 + qo*8);
#pragma unroll
        for (int nt = 0; nt < 2; nt++) {
            acc[mt][nt] = __builtin_amdgcn_mfma_f32_16x16x32_bf16(
                              fh8, wsl[0][nt], acc[mt][nt], 0, 0, 0);
            acc[mt][nt] = __builtin_amdgcn_mfma_f32_16x16x32_bf16(
                              fh8, wsh[0][nt], acc[mt][nt], 0, 0, 0);
        }
    }

    __syncthreads();   // barrier 2

    // writeback h via hardware packed cvt (RNE, = f2b)
#pragma unroll
    for (int nt = 0; nt < 2; nt++) {
        int c = n0 + 16*nt + l16;
        float k = kv[c], s = sv[c];
#pragma unroll
        for (int mt = 0; mt < 8; mt++) {
            int rbase = 16*mt + qo*4;
#pragma unroll
            for (int r = 0; r < 4; r += 2) {
                float h0 = fmaxf(fmaf(acc[mt][nt][r],   k, s), 0.f);
                float h1 = fmaxf(fmaf(acc[mt][nt][r+1], k, s), 0.f);
                unsigned int pk;
                asm("v_cvt_pk_bf16_f32 %0, %1, %2"
                    : "=v"(pk) : "v"(h0), "v"(h1));
                ah[(rbase + r    )*136 + c] = (ushort)(pk & 0xffffu);
                ah[(rbase + r + 1)*136 + c] = (ushort)(pk >> 16);
            }
        }
    }

    // GEMM2 preload slots {0,1}
#pragma unroll
    for (int ks = 0; ks < 2; ks++) {
        wsh[ks][0] = *(const short8*)(wh1 + wrow0*128 + ks*32 + qo*8);
        wsl[ks][0] = *(const short8*)(wl1 + wrow0*128 + ks*32 + qo*8);
        wsh[ks][1] = *(const short8*)(wh1 + wrow1*128 + ks*32 + qo*8);
        wsl[ks][1] = *(const short8*)(wl1 + wrow1*128 + ks*32 + qo*8);
    }
    __syncthreads();   // barrier 3

#pragma unroll
    for (int i = 0; i < 8; i++) {
        acc[i][0] = (floatx4){0.f,0.f,0.f,0.f};
        acc[i][1] = (floatx4){0.f,0.f,0.f,0.f};
    }
    // ks=0 (slot 0)
#pragma unroll
    for (int mt = 0; mt < 8; mt++) {
        short8 fh8 = *(const short8*)(ah + (16*mt + l16)*136 + qo*8);
#pragma unroll
        for (int nt = 0; nt < 2; nt++) {
            acc[mt][nt] = __builtin_amdgcn_mfma_f32_16x16x32_bf16(
                              fh8, wsl[0][nt], acc[mt][nt], 0, 0, 0);
            acc[mt][nt] = __builtin_amdgcn_mfma_f32_16x16x32_bf16(
                              fh8, wsh[0][nt], acc[mt][nt], 0, 0, 0);
        }
    }
    wsh[0][0] = *(const short8*)(wh1 + wrow0*128 + 64 + qo*8);
    wsl[0][0] = *(const short8*)(wl1 + wrow0*128 + 64 + qo*8);
    wsh[0][1] = *(const short8*)(wh1 + wrow1*128 + 64 + qo*8);
    wsl[0][1] = *(const short8*)(wl1 + wrow1*128 + 64 + qo*8);
    // ks=1 (slot 1)
#pragma unroll
    for (int mt = 0; mt < 8; mt++) {
        short8 fh8 = *(const short8*)(ah + (16*mt + l16)*136 + 32 + qo*8);
#pragma unroll
        for (int nt = 0; nt < 2; nt++) {
            acc[mt][nt] = __builtin_amdgcn_mfma_f32_16x16x32_bf16(
                              fh8, wsl[1][nt], acc[mt][nt], 0, 0, 0);
            acc[mt][nt] = __builtin_amdgcn_mfma_f32_16x16x32_bf16(
                              fh8, wsh[1][nt], acc[mt][nt], 0, 0, 0);
        }
    }
    wsh[1][0] = *(const short8*)(wh1 + wrow0*128 + 96 + qo*8);
    wsl[1][0] = *(const short8*)(wl1 + wrow0*128 + 96 + qo*8);
    wsh[1][1] = *(const short8*)(wh1 + wrow1*128 + 96 + qo*8);
    wsl[1][1] = *(const short8*)(wl1 + wrow1*128 + 96 + qo*8);
    // ks=2 (slot 0)
#pragma unroll
    for (int mt = 0; mt < 8; mt++) {
        short8 fh8 = *(const short8*)(ah + (16*mt + l16)*136 + 64 + qo*8);
#pragma unroll
        for (int nt = 0; nt < 2; nt++) {
            acc[mt][nt] = __builtin_amdgcn_mfma_f32_16x16x32_bf16(
                              fh8, wsl[0][nt], acc[mt][nt], 0, 0, 0);
            acc[mt][nt] = __builtin_amdgcn_mfma_f32_16x16x32_bf16(
                              fh8, wsh[0][nt], acc[mt][nt], 0, 0, 0);
        }
    }
    // ks=3 (slot 1)
#pragma unroll
    for (int mt = 0; mt < 8; mt++) {
        short8 fh8 = *(const short8*)(ah + (16*mt + l16)*136 + 96 + qo*8);
#pragma unroll
        for (int nt = 0; nt < 2; nt++) {
            acc[mt][nt] = __builtin_amdgcn_mfma_f32_16x16x32_bf16(
                              fh8, wsl[1][nt], acc[mt][nt], 0, 0, 0);
            acc[mt][nt] = __builtin_amdgcn_mfma_f32_16x16x32_bf16(
                              fh8, wsh[1][nt], acc[mt][nt], 0, 0, 0);
        }
    }

    // epilogue: stats2 (16-copy atomic staging) + per-group max/min
    float sum[2] = {0.f,0.f}, sq[2] = {0.f,0.f};
    float Mx[GM][2], Mn[GM][2];
#pragma unroll
    for (int g = 0; g < GM; g++) {
        Mx[g][0] = -3.4e38f; Mx[g][1] = -3.4e38f;
        Mn[g][0] =  3.4e38f; Mn[g][1] =  3.4e38f;
    }
#pragma unroll
    for (int mt = 0; mt < 8; mt++) {
        int gg = mt / TPG;
#pragma unroll
        for (int nt = 0; nt < 2; nt++)
#pragma unroll
            for (int r = 0; r < 4; r++) {
                float a = acc[mt][nt][r];
                sum[nt] += a; sq[nt] = fmaf(a, a, sq[nt]);
                Mx[gg][nt] = fmaxf(Mx[gg][nt], a);
                Mn[gg][nt] = fminf(Mn[gg][nt], a);
            }
    }
#pragma unroll
    for (int nt = 0; nt < 2; nt++) {
        sum[nt] += __shfl_xor(sum[nt], 16); sum[nt] += __shfl_xor(sum[nt], 32);
        sq[nt]  += __shfl_xor(sq[nt],  16); sq[nt]  += __shfl_xor(sq[nt],  32);
#pragma unroll
        for (int g = 0; g < GM; g++) {
            Mx[g][nt] = fmaxf(Mx[g][nt], __shfl_xor(Mx[g][nt], 16));
            Mx[g][nt] = fmaxf(Mx[g][nt], __shfl_xor(Mx[g][nt], 32));
            Mn[g][nt] = fminf(Mn[g][nt], __shfl_xor(Mn[g][nt], 16));
            Mn[g][nt] = fminf(Mn[g][nt], __shfl_xor(Mn[g][nt], 32));
        }
    }
    if (lane < 16) {
        float* dst = s2dst + (bx & 15) * 256;
#pragma unroll
        for (int nt = 0; nt < 2; nt++) {
            int c = n0 + 16*nt + lane;
            atomicAdd(&dst[c],       sum[nt]);
            atomicAdd(&dst[128 + c], sq[nt]);
#pragma unroll
            for (int g = 0; g < GM; g++) {
                mxo[(long long)(m0+g)*128 + c] = Mx[g][nt];
                mno[(long long)(m0+g)*128 + c] = Mn[g][nt];
            }
        }
    }
}

__global__ void __launch_bounds__(256, 4) sa_fused_both(
    const ushort* __restrict__ fh,
    const float* __restrict__ xyz, const float* __restrict__ nxyz,
    const int* __restrict__ idx0, const int* __restrict__ empty0,
    const ushort* __restrict__ wh00, const ushort* __restrict__ wl00,
    const ushort* __restrict__ wh01, const ushort* __restrict__ wl01,
    const float* __restrict__ g00, const float* __restrict__ b00,
    float* __restrict__ mx0, float* __restrict__ mn0, float invN0,
    const int* __restrict__ idx1, const int* __restrict__ empty1,
    const ushort* __restrict__ wh10, const ushort* __restrict__ wl10,
    const ushort* __restrict__ wh11, const ushort* __restrict__ wl11,
    const float* __restrict__ g10, const float* __restrict__ b10,
    float* __restrict__ mx1, float* __restrict__ mn1, float invN1,
    float* __restrict__ scop)
{
    __shared__ ushort ah[128*136];
    __shared__ float kv[128], sv[128];
    int t = threadIdx.x;
    if (blockIdx.x < MTOT/8)
        fused_body<16,8>(fh, xyz, nxyz, idx0, empty0,
                         wh00, wl00, wh01, wl01, g00, b00,
                         scop + 0, scop + 8192,
                         mx0, mn0, invN0, blockIdx.x, t, ah, kv, sv);
    else
        fused_body<32,4>(fh, xyz, nxyz, idx1, empty1,
                         wh10, wl10, wh11, wl11, g10, b10,
                         scop + 4096, scop + 12288,
                         mx1, mn1, invN1, blockIdx.x - MTOT/8, t, ah, kv, sv);
}

// ---------------------------------------------------------------------------
// Pass 3, reshaped: 1024 blocks x 8 rows. Each thread computes its channel's
// k/sh ONCE (16-copy sum) and reuses it for 8 outputs.
// ---------------------------------------------------------------------------
__global__ void __launch_bounds__(256, 1) sa_pass3b(
    const float* __restrict__ mx0, const float* __restrict__ mn0,
    const float* __restrict__ g01, const float* __restrict__ b01,
    const float* __restrict__ mx1, const float* __restrict__ mn1,
    const float* __restrict__ g11, const float* __restrict__ b11,
    const float* __restrict__ scop, float* __restrict__ outp,
    float invN0, float invN1)
{
    int t = threadIdx.x;
    int o = t;                 // output channel 0..255
    bool sc1 = o >= 128;
    int oc = o & 127;
    const float* sc = sc1 ? (scop + 12288) : (scop + 8192);
    float invN = sc1 ? invN1 : invN0;
    float gg   = sc1 ? g11[oc] : g01[oc];
    float bb   = sc1 ? b11[oc] : b01[oc];
    float sm = 0.f, sp = 0.f;
#pragma unroll
    for (int cp = 0; cp < 16; cp++) {
        sm += sc[cp*256 + oc];
        sp += sc[cp*256 + 128 + oc];
    }
    float mean = sm * invN;
    float var  = sp * invN - mean * mean;
    float k    = rsqrtf(var + 1e-5f) * gg;
    float sh   = bb - mean * k;
    const float* src = (k >= 0.f) ? (sc1 ? mx1 : mx0) : (sc1 ? mn1 : mn0);

    int m0 = blockIdx.x * 8;
#pragma unroll
    for (int j = 0; j < 8; j++) {
        int m = m0 + j;
        float v = src[(long long)m*128 + oc];
        float r = fmaf(v, k, sh);
        outp[(long long)m*256 + o] = r > 0.f ? r : 0.f;
    }
}

// ---------------------------------------------------------------------------
extern "C" void kernel_launch(void* const* d_in, const int* in_sizes, int n_in,
                              void* d_out, int out_size, void* d_ws, size_t ws_size,
                              hipStream_t stream)
{
    const float* xyz  = (const float*)d_in[0];
    const float* feat = (const float*)d_in[1];
    const float* nxyz = (const float*)d_in[2];
    const float* w00 = (const float*)d_in[5];
    const float* g00 = (const float*)d_in[6];
    const float* b00 = (const float*)d_in[7];
    const float* w01 = (const float*)d_in[8];
    const float* g01 = (const float*)d_in[9];
    const float* b01 = (const float*)d_in[10];
    const float* w10 = (const float*)d_in[11];
    const float* g10 = (const float*)d_in[12];
    const float* b10 = (const float*)d_in[13];
    const float* w11 = (const float*)d_in[14];
    const float* g11 = (const float*)d_in[15];
    const float* b11 = (const float*)d_in[16];
    float* out = (float*)d_out;

    char*  wsb    = (char*)d_ws;
    int*   idx0   = (int*)(wsb + 4096);
    int*   idx1   = (int*)(wsb + 4096 + 524288);
    int*   empty0 = (int*)(wsb + 4096 + 524288 + 1048576);
    int*   empty1 = (int*)(wsb + 4096 + 524288 + 1048576 + 32768);
    ushort* fh    = (ushort*)(wsb + 2000000);    // 4 MB
    float* mx0    = (float*)(wsb + 150000000);
    float* mn0    = (float*)(wsb + 155000000);
    float* mx1    = (float*)(wsb + 160000000);
    float* mn1    = (float*)(wsb + 165000000);
    ushort* wh01  = (ushort*)(wsb + 170000000);
    ushort* wl01  = (ushort*)(wsb + 171000000);
    ushort* wh11  = (ushort*)(wsb + 172000000);
    ushort* wl11  = (ushort*)(wsb + 173000000);
    ushort* wh00  = (ushort*)(wsb + 174000000);
    ushort* wl00  = (ushort*)(wsb + 175000000);
    ushort* wh10  = (ushort*)(wsb + 176000000);
    ushort* wl10  = (ushort*)(wsb + 177000000);
    float* scop   = (float*)(wsb + 180000000);   // 4 x 16 x 256 floats = 64 KB

    const float invN0 = 1.0f / (float)(MTOT*16);
    const float invN1 = 1.0f / (float)(MTOT*32);
    float* fout = out + MTOT*3;

    // 1: ballq (blocks 0..2047) + prep (blocks 2048..4095; zeroes scop)
    StackSAModuleMSG_85761906966880_kernel<<<MTOT/4 + 2048, 256, 0, stream>>>(
        xyz, nxyz, out, scop, feat, fh,
        idx0, idx1, empty0, empty1,
        w00, w01, w10, w11,
        wh00, wl00, wh01, wl01, wh10, wl10, wh11, wl11);

    // 2: stats1 -> 16-copy staging
    sa_stats1_both<<<MTOT/8 + MTOT/4, 256, 0, stream>>>(
        fh, xyz, nxyz,
        idx0, empty0, wh00,
        idx1, empty1, wh10, scop);

    // 3: fused (reads s1 copies; writes s2 copies + max/min)
    sa_fused_both<<<MTOT/8 + MTOT/4, 256, 0, stream>>>(
        fh, xyz, nxyz,
        idx0, empty0, wh00, wl00, wh01, wl01, g00, b00,
        mx0, mn0, invN0,
        idx1, empty1, wh10, wl10, wh11, wl11, g10, b10,
        mx1, mn1, invN1, scop);

    // 4: pass3 (1024 blocks x 8 rows; per-thread k/sh computed once)
    sa_pass3b<<<1024, 256, 0, stream>>>(
        mx0, mn0, g01, b01, mx1, mn1, g11, b11, scop, fout, invN0, invN1);

    hipError_t e = hipGetLastError();
    if (e != hipSuccess) EPR("[KL] enqueue err=%d (%s)\n", (int)e, hipGetErrorString(e));
}